// Round 17
// baseline (1006.249 us; speedup 1.0000x reference)
//
#include <hip/hip_runtime.h>
#include <hip/hip_bf16.h>

// ---------------------------------------------------------------------------
// RingLlamaAttention on MI355X (gfx950)
// batched cast f32->bf16 | rope tables | vT gemm, then Q,K gemms (256^2,
// RoPE fused in epilogue; K last to leave its tail L2-warm) | flash attention
// (QBLK=64, kv-loop REVERSED to start on L2-warm K, K+V dbuf via gload_lds,
// XCD-aware swizzle, per-lane defer-max, exp2 softmax, deferred l-reduce,
// setprio) | O gemm (256^2) -> f32 out
// Shapes: B=2, S=4096, s_local=1024, H=4096, nh=32, hd=128, K=4096
// ---------------------------------------------------------------------------

using bf16x8 = __attribute__((ext_vector_type(8))) short;
using f32x4  = __attribute__((ext_vector_type(4))) float;

__device__ inline unsigned short f32_to_bf16_bits(float f) {
  unsigned int u = __float_as_uint(f);
  u += 0x7FFFu + ((u >> 16) & 1u);   // round-to-nearest-even
  return (unsigned short)(u >> 16);
}
__device__ inline float bf16_bits_to_f32(unsigned short h) {
  return __uint_as_float(((unsigned int)h) << 16);
}
__device__ inline unsigned short f32_to_bf16_fast(float f) {
  __hip_bfloat16 hb = __float2bfloat16(f);
  unsigned short us;
  __builtin_memcpy(&us, &hb, 2);
  return us;
}

// async global->LDS, 16B per lane (dest must be wave-uniform base + lane*16)
__device__ __forceinline__ void load_lds16(const unsigned short* g, unsigned short* l) {
  __builtin_amdgcn_global_load_lds(
      (const __attribute__((address_space(1))) void*)g,
      (__attribute__((address_space(3))) void*)l, 16, 0, 0);
}

// ---- batched f32 -> bf16 cast: one launch for hs + 4 weight matrices ----
__global__ void cast_f32_bf16_batched(const float* __restrict__ hs,
                                      const float* __restrict__ w0,
                                      const float* __restrict__ w1,
                                      const float* __restrict__ w2,
                                      const float* __restrict__ w3,
                                      unsigned short* __restrict__ out) {
  const long hs4 = 2L * 4096 * 4096 / 4;
  const long w4  = 4096L * 4096 / 4;
  long i = (long)blockIdx.x * blockDim.x + threadIdx.x;
  long stride = (long)gridDim.x * blockDim.x;
  const long total = hs4 + 4 * w4;
  for (; i < total; i += stride) {
    const float* src;
    long j = i;
    if (j < hs4) { src = hs; }
    else {
      j -= hs4;
      long wi = j / w4;
      j -= wi * w4;
      src = (wi == 0) ? w0 : (wi == 1) ? w1 : (wi == 2) ? w2 : w3;
    }
    float4 v = reinterpret_cast<const float4*>(src)[j];
    ushort4 o;
    o.x = f32_to_bf16_bits(v.x);
    o.y = f32_to_bf16_bits(v.y);
    o.z = f32_to_bf16_bits(v.z);
    o.w = f32_to_bf16_bits(v.w);
    reinterpret_cast<ushort4*>(out)[i] = o;
  }
}

// ---- RoPE cos/sin tables ----
__global__ void rope_tables(float* __restrict__ cos_t, float* __restrict__ sin_t) {
  int idx = blockIdx.x * 256 + threadIdx.x;
  if (idx >= 4096 * 64) return;
  int p = idx >> 6, i = idx & 63;
  float inv = __expf(-(float)i * (9.210340371976184f / 64.0f));  // theta^(-i/64)
  float f = (float)p * inv;
  cos_t[idx] = cosf(f);
  sin_t[idx] = sinf(f);
}

__device__ inline void storeC(float* p, float v) { *p = v; }
__device__ inline void storeC(unsigned short* p, float v) { *p = f32_to_bf16_bits(v); }

// ---- 256^2 depth-2 pipelined GEMM (verified R5); optional fused RoPE ----
#define STG2(Gb, Lb, h, kc)                                                    \
  load_lds16((Gb) + (long)((h) * 128 + srow) * 4096 + sslot * 8 + (kc),        \
             (Lb) + tid * 8);                                                  \
  load_lds16((Gb) + (long)((h) * 128 + 64 + srow) * 4096 + sslot * 8 + (kc),   \
             (Lb) + 4096 + tid * 8);

#define MFMAQ(MH, NH)                                                          \
  _Pragma("unroll") for (int mi = 0; mi < 4; ++mi)                             \
    _Pragma("unroll") for (int ni = 0; ni < 2; ++ni)                           \
      _Pragma("unroll") for (int kk = 0; kk < 2; ++kk)                         \
        acc[(MH) * 4 + mi][(NH) * 2 + ni] =                                    \
            __builtin_amdgcn_mfma_f32_16x16x32_bf16(                           \
                a[mi][kk], b[(NH) * 2 + ni][kk],                               \
                acc[(MH) * 4 + mi][(NH) * 2 + ni], 0, 0, 0);

#define TILE(P, KC, MODE)                                                      \
  {                                                                            \
    const unsigned short* Ar = lds + wm * 16384 + (P) * 8192;                  \
    const unsigned short* Br = brw + (P) * 8192;                               \
    _Pragma("unroll") for (int mf = 0; mf < 4; ++mf) {                         \
      a[mf][0] = *reinterpret_cast<const bf16x8*>(Ar + mf * 1024 + ao0);       \
      a[mf][1] = *reinterpret_cast<const bf16x8*>(Ar + mf * 1024 + ao1);       \
    }                                                                          \
    _Pragma("unroll") for (int nf = 0; nf < 2; ++nf) {                         \
      b[nf][0] = *reinterpret_cast<const bf16x8*>(Br + boff[nf] + ao0);        \
      b[nf][1] = *reinterpret_cast<const bf16x8*>(Br + boff[nf] + ao1);        \
    }                                                                          \
    __builtin_amdgcn_s_setprio(1);                                             \
    MFMAQ(0, 0);                                                               \
    __builtin_amdgcn_s_setprio(0);                                             \
    _Pragma("unroll") for (int nf = 2; nf < 4; ++nf) {                         \
      b[nf][0] = *reinterpret_cast<const bf16x8*>(Br + boff[nf] + ao0);        \
      b[nf][1] = *reinterpret_cast<const bf16x8*>(Br + boff[nf] + ao1);        \
    }                                                                          \
    __builtin_amdgcn_s_setprio(1);                                             \
    MFMAQ(0, 1);                                                               \
    __builtin_amdgcn_s_setprio(0);                                             \
    asm volatile("s_waitcnt lgkmcnt(0)" ::: "memory");                         \
    asm volatile("s_barrier" ::: "memory"); /* B[.][P] fully read */           \
    if ((MODE) == 0) {                                                         \
      STG2(Bg, lds + 32768 + (P) * 8192, 0, KC);                               \
      STG2(Bg, lds + 49152 + (P) * 8192, 1, KC);                               \
    }                                                                          \
    _Pragma("unroll") for (int mf = 0; mf < 4; ++mf) {                         \
      a[mf][0] = *reinterpret_cast<const bf16x8*>(Ar + (4 + mf) * 1024 + ao0); \
      a[mf][1] = *reinterpret_cast<const bf16x8*>(Ar + (4 + mf) * 1024 + ao1); \
    }                                                                          \
    __builtin_amdgcn_s_setprio(1);                                             \
    MFMAQ(1, 0);                                                               \
    __builtin_amdgcn_s_setprio(0);                                             \
    asm volatile("s_waitcnt lgkmcnt(0)" ::: "memory");                         \
    asm volatile("s_barrier" ::: "memory"); /* A[.][P] fully read */           \
    if ((MODE) == 0) {                                                         \
      STG2(Ag, lds + (P) * 8192, 0, KC);                                       \
      STG2(Ag, lds + 16384 + (P) * 8192, 1, KC);                               \
    }                                                                          \
    __builtin_amdgcn_s_setprio(1);                                             \
    MFMAQ(1, 1);                                                               \
    __builtin_amdgcn_s_setprio(0);                                             \
    if ((MODE) == 0) asm volatile("s_waitcnt vmcnt(8)" ::: "memory");          \
    if ((MODE) == 1) asm volatile("s_waitcnt vmcnt(0)" ::: "memory");          \
    asm volatile("s_barrier" ::: "memory"); /* next tile's data landed */      \
  }

template <typename OUT_T, bool ROPE>
__global__ __launch_bounds__(512, 2) void gemm256(const unsigned short* __restrict__ A,
                                                  const unsigned short* __restrict__ B,
                                                  OUT_T* __restrict__ C,
                                                  long Astride_z, long Cstride_z, int N,
                                                  const float* __restrict__ cos_t,
                                                  const float* __restrict__ sin_t,
                                                  float gain) {
  __shared__ unsigned short lds[65536];   // 128 KiB
  const int tid = threadIdx.x;
  const int bn = blockIdx.x, bm = blockIdx.y, bz = blockIdx.z;
  const unsigned short* Ag = A + (long)bz * Astride_z + (long)bm * 256 * 4096;
  const unsigned short* Bg = B + (long)bn * 256 * 4096;

  const int w = tid >> 6, lane = tid & 63;
  const int wm = w >> 2, wn = w & 3;
  const int fr = lane & 15, fg = lane >> 4;
  const int ao0 = fr * 64 + ((fg ^ (fr & 7)) * 8);
  const int ao1 = fr * 64 + (((4 + fg) ^ (fr & 7)) * 8);
  const int srow = tid >> 3;
  const int sslot = (tid & 7) ^ (srow & 7);

  const unsigned short* brw =
      lds + 32768 + (wn >> 1) * 16384 + (ROPE ? (wn & 1) * 2048 : (wn & 1) * 4096);
  int boff[4];
#pragma unroll
  for (int nf = 0; nf < 4; ++nf)
    boff[nf] = ROPE ? ((nf & 1) * 1024 + (nf >> 1) * 4096) : nf * 1024;

  f32x4 acc[8][4] = {};
  bf16x8 a[4][2], b[4][2];

  STG2(Ag, lds + 0, 0, 0);     STG2(Ag, lds + 16384, 1, 0);
  STG2(Bg, lds + 32768, 0, 0); STG2(Bg, lds + 49152, 1, 0);
  STG2(Ag, lds + 8192, 0, 64);  STG2(Ag, lds + 24576, 1, 64);
  STG2(Bg, lds + 40960, 0, 64); STG2(Bg, lds + 57344, 1, 64);
  asm volatile("s_waitcnt vmcnt(8)" ::: "memory");
  asm volatile("s_barrier" ::: "memory");

  for (int ti = 0; ti < 31; ++ti) {        // tiles 0..61
    TILE(0, (2 * ti + 2) * 64, 0);
    TILE(1, (2 * ti + 3) * 64, 0);
  }
  TILE(0, 0, 1);
  TILE(1, 0, 2);

  OUT_T* Cb = C + (long)bz * Cstride_z + ((long)bm * 256) * N + bn * 256;
  if constexpr (ROPE) {
    const int head = wn >> 1, q = wn & 1;
#pragma unroll
    for (int mf = 0; mf < 8; ++mf)
#pragma unroll
      for (int nf = 0; nf < 2; ++nf)
#pragma unroll
        for (int rr = 0; rr < 4; ++rr) {
          int row = wm * 128 + mf * 16 + fg * 4 + rr;
          int pos = bm * 256 + row;              // token pos (Q<1024, K<4096)
          int d = q * 32 + nf * 16 + fr;         // d in [0,64)
          float c = cos_t[pos * 64 + d];
          float s = sin_t[pos * 64 + d];
          float x1 = acc[mf][nf][rr];            // col head*128 + d
          float x2 = acc[mf][nf + 2][rr];        // col head*128 + 64 + d
          storeC(Cb + (long)row * N + head * 128 + d, (x1 * c - x2 * s) * gain);
          storeC(Cb + (long)row * N + head * 128 + 64 + d, (x2 * c + x1 * s) * gain);
        }
  } else {
#pragma unroll
    for (int mf = 0; mf < 8; ++mf)
#pragma unroll
      for (int nf = 0; nf < 4; ++nf)
#pragma unroll
        for (int rr = 0; rr < 4; ++rr) {
          int row = wm * 128 + mf * 16 + fg * 4 + rr;
          int col = wn * 64 + nf * 16 + fr;
          storeC(Cb + (long)row * N + col, acc[mf][nf][rr]);
        }
  }
}

// ---- flash attention (R15 structure; kv-loop reversed for L2-warm start) ----
__global__ __launch_bounds__(256) void attn_fwd(const unsigned short* __restrict__ qb,
                                                const unsigned short* __restrict__ kb,
                                                const unsigned short* __restrict__ vT,
                                                unsigned short* __restrict__ ob) {
  __shared__ unsigned short Ks[2][64 * 128];   // 16KB x2
  __shared__ unsigned short Vl[2][128 * 64];   // 16KB x2
  __shared__ unsigned short Ps[4][16 * 72];    // 9KB

  const int id = blockIdx.x;
  const int xcd = id & 7, j = id >> 3;
  const int hb = xcd + 8 * (j >> 4);
  const int qt = j & 15;
  const int h = hb & 31, b = hb >> 5;

  const int tid = threadIdx.x, w = tid >> 6, lane = tid & 63;
  const int fr = lane & 15, fg = lane >> 4;

  const unsigned short* kbase = kb + (long)b * 4096 * 4096 + h * 128;
  const unsigned short* vbase = vT + (long)h * 128 * 8192 + (long)b * 4096;

  // persistent staging pointers, starting at tile 62 and DECREMENTING
  const unsigned short* kp[4];
  const unsigned short* vp[4];
  unsigned short* kl[4];
  unsigned short* vl[4];
#pragma unroll
  for (int i = 0; i < 4; i++) {
    int c = tid + 256 * i;
    int key = c >> 4, s0 = c & 15;
    kp[i] = kbase + (long)(62 * 64 + key) * 4096 + (s0 ^ (key & 15)) * 8;
    kl[i] = (unsigned short*)&Ks[0][c * 8];
    int f0 = c >> 3, s1 = c & 7;
    vp[i] = vbase + (long)f0 * 8192 + 62 * 64 + (s1 ^ (f0 & 7)) * 8;
    vl[i] = (unsigned short*)&Vl[0][c * 8];
  }
  const int pelem = 64 * 128;

  // Q fragments: row = fr, k = fg*8 + c*32
  bf16x8 qf[4];
  {
    const unsigned short* qptr =
        qb + ((long)b * 1024 + qt * 64 + w * 16 + fr) * 4096 + h * 128 + fg * 8;
#pragma unroll
    for (int c = 0; c < 4; c++) qf[c] = *reinterpret_cast<const bf16x8*>(qptr + c * 32);
  }

  f32x4 outa[8] = {};
  float m_run[4], l_run[4];
#pragma unroll
  for (int r = 0; r < 4; r++) { m_run[r] = -1e30f; l_run[r] = 0.0f; }

  // prologue: stage tile 63 (freshest K rows, L2-warm) into parity 0
#pragma unroll
  for (int i = 0; i < 4; i++) {
    int c = tid + 256 * i;
    int key = c >> 4, s0 = c & 15;
    load_lds16(kbase + (long)(63 * 64 + key) * 4096 + (s0 ^ (key & 15)) * 8,
               &Ks[0][c * 8]);
    int f0 = c >> 3, s1 = c & 7;
    load_lds16(vbase + (long)f0 * 8192 + 63 * 64 + (s1 ^ (f0 & 7)) * 8,
               &Vl[0][c * 8]);
  }
  asm volatile("s_waitcnt vmcnt(0)" ::: "memory");
  asm volatile("s_barrier" ::: "memory");

  for (int it = 0; it < 64; ++it) {   // processes tile 63-it
    const int cur = it & 1;
    if (it < 63) {
      const int po = (cur ^ 1) * pelem;
#pragma unroll
      for (int i = 0; i < 4; i++) {
        load_lds16(kp[i], kl[i] + po);
        kp[i] -= 64 * 4096;
        load_lds16(vp[i], vl[i] + po);
        vp[i] -= 64;
      }
    }

    // S = Q K^T : 4 key-subtiles of 16
    f32x4 sacc[4];
    __builtin_amdgcn_s_setprio(1);
#pragma unroll
    for (int ks = 0; ks < 4; ks++) {
      f32x4 aq = {0.f, 0.f, 0.f, 0.f};
#pragma unroll
      for (int cc = 0; cc < 4; cc++) {
        bf16x8 kf = *reinterpret_cast<const bf16x8*>(
            &Ks[cur][(ks * 16 + fr) * 128 + (((cc * 4 + fg) ^ fr) & 15) * 8]);
        aq = __builtin_amdgcn_mfma_f32_16x16x32_bf16(qf[cc], kf, aq, 0, 0, 0);
      }
      sacc[ks] = aq;
    }
    __builtin_amdgcn_s_setprio(0);

    // per-lane defer-max (cross-lane reduce only when bound triggers)
    float mxl[4];
    int need = 0;
#pragma unroll
    for (int r = 0; r < 4; r++) {
      mxl[r] = fmaxf(fmaxf(sacc[0][r], sacc[1][r]), fmaxf(sacc[2][r], sacc[3][r]));
      need |= (mxl[r] > m_run[r] + 11.5f) ? 1 : 0;
    }
    if (__any(need)) {   // rare: full row max reduce + rescale
#pragma unroll
      for (int r = 0; r < 4; r++) {
        float mx = mxl[r];
        mx = fmaxf(mx, __shfl_xor(mx, 1));
        mx = fmaxf(mx, __shfl_xor(mx, 2));
        mx = fmaxf(mx, __shfl_xor(mx, 4));
        mx = fmaxf(mx, __shfl_xor(mx, 8));
        float mnew = fmaxf(m_run[r], mx);
        float ef = exp2f(m_run[r] - mnew);
        l_run[r] *= ef;
        m_run[r] = mnew;
#pragma unroll
        for (int ds = 0; ds < 8; ds++) outa[ds][r] *= ef;
      }
    }
#pragma unroll
    for (int r = 0; r < 4; r++) {
      float sum = 0.f;
#pragma unroll
      for (int ks = 0; ks < 4; ks++) {
        float pv = exp2f(sacc[ks][r] - m_run[r]);   // <= 2^11.5
        Ps[w][(fg * 4 + r) * 72 + ks * 16 + fr] = f32_to_bf16_fast(pv);
        sum += pv;
      }
      l_run[r] += sum;
    }

    // O += P V
    __builtin_amdgcn_s_setprio(1);
#pragma unroll
    for (int c2 = 0; c2 < 2; c2++) {
      bf16x8 pf = *reinterpret_cast<const bf16x8*>(&Ps[w][fr * 72 + c2 * 32 + fg * 8]);
#pragma unroll
      for (int ds = 0; ds < 8; ds++) {
        int feat = ds * 16 + fr;
        int pch = ((c2 * 4 + fg) ^ (feat & 7)) & 7;
        bf16x8 vf = *reinterpret_cast<const bf16x8*>(&Vl[cur][feat * 64 + pch * 8]);
        outa[ds] = __builtin_amdgcn_mfma_f32_16x16x32_bf16(pf, vf, outa[ds], 0, 0, 0);
      }
    }
    __builtin_amdgcn_s_setprio(0);

    if (it < 63) {
      asm volatile("s_waitcnt vmcnt(0) lgkmcnt(0)" ::: "memory");
      asm volatile("s_barrier" ::: "memory");
    }
  }

  // final cross-lane l reduce (16 fr lanes), normalize, store
#pragma unroll
  for (int r = 0; r < 4; r++) {
    float l = l_run[r];
    l += __shfl_xor(l, 1);
    l += __shfl_xor(l, 2);
    l += __shfl_xor(l, 4);
    l += __shfl_xor(l, 8);
    float inv = 1.0f / l;
    unsigned short* op =
        ob + ((long)b * 1024 + qt * 64 + w * 16 + fg * 4 + r) * 4096 + h * 128;
#pragma unroll
    for (int ds = 0; ds < 8; ds++) op[ds * 16 + fr] = f32_to_bf16_bits(outa[ds][r] * inv);
  }
}

// ---------------------------------------------------------------------------
extern "C" void kernel_launch(void* const* d_in, const int* in_sizes, int n_in,
                              void* d_out, int out_size, void* d_ws, size_t ws_size,
                              hipStream_t stream) {
  const float* hs = (const float*)d_in[0];
  const float* wq = (const float*)d_in[1];
  const float* wk = (const float*)d_in[2];
  const float* wv = (const float*)d_in[3];
  const float* wo = (const float*)d_in[4];
  float* out = (float*)d_out;

  const long hsN = 2L * 4096 * 4096;
  const long wN  = 4096L * 4096;

  unsigned short* hs_b = (unsigned short*)d_ws;
  unsigned short* wq_b = hs_b + hsN;
  unsigned short* wk_b = wq_b + wN;
  unsigned short* wv_b = wk_b + wN;
  unsigned short* wo_b = wv_b + wN;
  unsigned short* q_b  = wo_b + wN;             // 2048 x 4096
  unsigned short* k_b  = q_b + 2048L * 4096;    // 8192 x 4096 ([tok][feat])
  unsigned short* vT_b = k_b + 8192L * 4096;    // 4096 x 8192 ([feat][tok])
  unsigned short* at_b = vT_b + 8192L * 4096;   // 2048 x 4096
  float* cos_t = (float*)(at_b + 2048L * 4096);
  float* sin_t = cos_t + 4096 * 64;

  cast_f32_bf16_batched<<<dim3(8192), dim3(256), 0, stream>>>(
      hs, wq, wk, wv, wo, hs_b);

  rope_tables<<<dim3(1024), dim3(256), 0, stream>>>(cos_t, sin_t);

  const float qgain = 0.08838834764831845f * 1.4426950408889634f;
  // vT first (so its 134MB write doesn't evict K later)
  gemm256<unsigned short, false><<<dim3(32, 16, 1), dim3(512), 0, stream>>>(
      wv_b, hs_b, vT_b, 0L, 0L, 8192, cos_t, sin_t, 1.0f);
  // Q gemm with fused RoPE (+ exp2-domain gain)
  gemm256<unsigned short, true><<<dim3(16, 4, 2), dim3(512), 0, stream>>>(
      hs_b, wq_b, q_b, 4096L * 4096, 1024L * 4096, 4096, cos_t, sin_t, qgain);
  // K gemm with fused RoPE — LAST big write before attn (tail stays L2-warm)
  gemm256<unsigned short, true><<<dim3(16, 16, 2), dim3(512), 0, stream>>>(
      hs_b, wk_b, k_b, 4096L * 4096, 4096L * 4096, 4096, cos_t, sin_t, 1.0f);

  // attention — flat grid with XCD-aware decode; kv-loop runs high->low
  attn_fwd<<<dim3(1024), dim3(256), 0, stream>>>(q_b, k_b, vT_b, at_b);

  // O projection — plain, f32 out
  gemm256<float, false><<<dim3(16, 8, 1), dim3(512), 0, stream>>>(
      at_b, wo_b, out, 0L, 0L, 4096, cos_t, sin_t, 1.0f);
}

// Round 18
// 983.122 us; speedup vs baseline: 1.0235x; 1.0235x over previous
//
#include <hip/hip_runtime.h>
#include <hip/hip_bf16.h>

// ---------------------------------------------------------------------------
// RingLlamaAttention on MI355X (gfx950)
// batched cast f32->bf16 | rope tables | FUSED vT+Q+K gemm launch (1152
// blocks; 256^2 pipelined, RoPE fused for Q/K, K region last => L2-warm) |
// flash attention (QBLK=64, reversed kv-loop, K+V dbuf via gload_lds,
// XCD-aware swizzle, per-lane defer-max, exp2 softmax, deferred l-reduce,
// setprio) | O gemm (256^2) -> f32 out
// Shapes: B=2, S=4096, s_local=1024, H=4096, nh=32, hd=128, K=4096
// ---------------------------------------------------------------------------

using bf16x8 = __attribute__((ext_vector_type(8))) short;
using f32x4  = __attribute__((ext_vector_type(4))) float;

__device__ inline unsigned short f32_to_bf16_bits(float f) {
  unsigned int u = __float_as_uint(f);
  u += 0x7FFFu + ((u >> 16) & 1u);   // round-to-nearest-even
  return (unsigned short)(u >> 16);
}
__device__ inline float bf16_bits_to_f32(unsigned short h) {
  return __uint_as_float(((unsigned int)h) << 16);
}
__device__ inline unsigned short f32_to_bf16_fast(float f) {
  __hip_bfloat16 hb = __float2bfloat16(f);
  unsigned short us;
  __builtin_memcpy(&us, &hb, 2);
  return us;
}

// async global->LDS, 16B per lane (dest must be wave-uniform base + lane*16)
__device__ __forceinline__ void load_lds16(const unsigned short* g, unsigned short* l) {
  __builtin_amdgcn_global_load_lds(
      (const __attribute__((address_space(1))) void*)g,
      (__attribute__((address_space(3))) void*)l, 16, 0, 0);
}

// ---- batched f32 -> bf16 cast: one launch for hs + 4 weight matrices ----
__global__ void cast_f32_bf16_batched(const float* __restrict__ hs,
                                      const float* __restrict__ w0,
                                      const float* __restrict__ w1,
                                      const float* __restrict__ w2,
                                      const float* __restrict__ w3,
                                      unsigned short* __restrict__ out) {
  const long hs4 = 2L * 4096 * 4096 / 4;
  const long w4  = 4096L * 4096 / 4;
  long i = (long)blockIdx.x * blockDim.x + threadIdx.x;
  long stride = (long)gridDim.x * blockDim.x;
  const long total = hs4 + 4 * w4;
  for (; i < total; i += stride) {
    const float* src;
    long j = i;
    if (j < hs4) { src = hs; }
    else {
      j -= hs4;
      long wi = j / w4;
      j -= wi * w4;
      src = (wi == 0) ? w0 : (wi == 1) ? w1 : (wi == 2) ? w2 : w3;
    }
    float4 v = reinterpret_cast<const float4*>(src)[j];
    ushort4 o;
    o.x = f32_to_bf16_bits(v.x);
    o.y = f32_to_bf16_bits(v.y);
    o.z = f32_to_bf16_bits(v.z);
    o.w = f32_to_bf16_bits(v.w);
    reinterpret_cast<ushort4*>(out)[i] = o;
  }
}

// ---- RoPE cos/sin tables ----
__global__ void rope_tables(float* __restrict__ cos_t, float* __restrict__ sin_t) {
  int idx = blockIdx.x * 256 + threadIdx.x;
  if (idx >= 4096 * 64) return;
  int p = idx >> 6, i = idx & 63;
  float inv = __expf(-(float)i * (9.210340371976184f / 64.0f));  // theta^(-i/64)
  float f = (float)p * inv;
  cos_t[idx] = cosf(f);
  sin_t[idx] = sinf(f);
}

__device__ inline void storeC(float* p, float v) { *p = v; }
__device__ inline void storeC(unsigned short* p, float v) { *p = f32_to_bf16_bits(v); }

// ---- 256^2 depth-2 pipelined GEMM core macros (verified R5 ledger) ----
#define STG2(Gb, Lb, h, kc)                                                    \
  load_lds16((Gb) + (long)((h) * 128 + srow) * 4096 + sslot * 8 + (kc),        \
             (Lb) + tid * 8);                                                  \
  load_lds16((Gb) + (long)((h) * 128 + 64 + srow) * 4096 + sslot * 8 + (kc),   \
             (Lb) + 4096 + tid * 8);

#define MFMAQ(MH, NH)                                                          \
  _Pragma("unroll") for (int mi = 0; mi < 4; ++mi)                             \
    _Pragma("unroll") for (int ni = 0; ni < 2; ++ni)                           \
      _Pragma("unroll") for (int kk = 0; kk < 2; ++kk)                         \
        acc[(MH) * 4 + mi][(NH) * 2 + ni] =                                    \
            __builtin_amdgcn_mfma_f32_16x16x32_bf16(                           \
                a[mi][kk], b[(NH) * 2 + ni][kk],                               \
                acc[(MH) * 4 + mi][(NH) * 2 + ni], 0, 0, 0);

#define TILE(P, KC, MODE)                                                      \
  {                                                                            \
    const unsigned short* Ar = lds + wm * 16384 + (P) * 8192;                  \
    const unsigned short* Br = brw + (P) * 8192;                               \
    _Pragma("unroll") for (int mf = 0; mf < 4; ++mf) {                         \
      a[mf][0] = *reinterpret_cast<const bf16x8*>(Ar + mf * 1024 + ao0);       \
      a[mf][1] = *reinterpret_cast<const bf16x8*>(Ar + mf * 1024 + ao1);       \
    }                                                                          \
    _Pragma("unroll") for (int nf = 0; nf < 2; ++nf) {                         \
      b[nf][0] = *reinterpret_cast<const bf16x8*>(Br + boff[nf] + ao0);        \
      b[nf][1] = *reinterpret_cast<const bf16x8*>(Br + boff[nf] + ao1);        \
    }                                                                          \
    __builtin_amdgcn_s_setprio(1);                                             \
    MFMAQ(0, 0);                                                               \
    __builtin_amdgcn_s_setprio(0);                                             \
    _Pragma("unroll") for (int nf = 2; nf < 4; ++nf) {                         \
      b[nf][0] = *reinterpret_cast<const bf16x8*>(Br + boff[nf] + ao0);        \
      b[nf][1] = *reinterpret_cast<const bf16x8*>(Br + boff[nf] + ao1);        \
    }                                                                          \
    __builtin_amdgcn_s_setprio(1);                                             \
    MFMAQ(0, 1);                                                               \
    __builtin_amdgcn_s_setprio(0);                                             \
    asm volatile("s_waitcnt lgkmcnt(0)" ::: "memory");                         \
    asm volatile("s_barrier" ::: "memory"); /* B[.][P] fully read */           \
    if ((MODE) == 0) {                                                         \
      STG2(Bg, lds + 32768 + (P) * 8192, 0, KC);                               \
      STG2(Bg, lds + 49152 + (P) * 8192, 1, KC);                               \
    }                                                                          \
    _Pragma("unroll") for (int mf = 0; mf < 4; ++mf) {                         \
      a[mf][0] = *reinterpret_cast<const bf16x8*>(Ar + (4 + mf) * 1024 + ao0); \
      a[mf][1] = *reinterpret_cast<const bf16x8*>(Ar + (4 + mf) * 1024 + ao1); \
    }                                                                          \
    __builtin_amdgcn_s_setprio(1);                                             \
    MFMAQ(1, 0);                                                               \
    __builtin_amdgcn_s_setprio(0);                                             \
    asm volatile("s_waitcnt lgkmcnt(0)" ::: "memory");                         \
    asm volatile("s_barrier" ::: "memory"); /* A[.][P] fully read */           \
    if ((MODE) == 0) {                                                         \
      STG2(Ag, lds + (P) * 8192, 0, KC);                                       \
      STG2(Ag, lds + 16384 + (P) * 8192, 1, KC);                               \
    }                                                                          \
    __builtin_amdgcn_s_setprio(1);                                             \
    MFMAQ(1, 1);                                                               \
    __builtin_amdgcn_s_setprio(0);                                             \
    if ((MODE) == 0) asm volatile("s_waitcnt vmcnt(8)" ::: "memory");          \
    if ((MODE) == 1) asm volatile("s_waitcnt vmcnt(0)" ::: "memory");          \
    asm volatile("s_barrier" ::: "memory"); /* next tile's data landed */      \
  }

// ---- fused vT + Q + K launch: 1152 blocks, block-uniform region decode ----
// id 0-511: vT[feat][tok]=Wv*hs^T (plain). id 512-639: Q (RoPE, gain).
// id 640-1151: K (RoPE) — dispatched last so its tail stays L2-warm for attn.
__global__ __launch_bounds__(512, 2) void gemm_qkv(
    const unsigned short* __restrict__ hsb, const unsigned short* __restrict__ wvb,
    const unsigned short* __restrict__ wqb, const unsigned short* __restrict__ wkb,
    unsigned short* __restrict__ vTb, unsigned short* __restrict__ qob,
    unsigned short* __restrict__ kob, const float* __restrict__ cos_t,
    const float* __restrict__ sin_t, float qgain) {
  __shared__ unsigned short lds[65536];   // 128 KiB
  const int tid = threadIdx.x;
  const int id = blockIdx.x;

  const unsigned short *Ag, *Bg;
  unsigned short* Cb;
  int N, posbase;
  float gain;
  bool rope;
  if (id < 512) {                       // vT: A=wv (16 bm), B=hs (32 bn)
    int bn = id & 31, bm = id >> 5;
    rope = false; N = 8192; gain = 1.0f; posbase = 0;
    Ag = wvb + (long)bm * 256 * 4096;
    Bg = hsb + (long)bn * 256 * 4096;
    Cb = vTb + (long)bm * 256 * 8192 + bn * 256;
  } else if (id < 640) {                // Q: (16 bn, 4 bm, 2 bz)
    int j = id - 512;
    int bn = j & 15, bm = (j >> 4) & 3, bz = j >> 6;
    rope = true; N = 4096; gain = qgain; posbase = bm * 256;
    Ag = hsb + (long)bz * 4096 * 4096 + (long)bm * 256 * 4096;
    Bg = wqb + (long)bn * 256 * 4096;
    Cb = qob + (long)bz * 1024 * 4096 + (long)bm * 256 * 4096 + bn * 256;
  } else {                              // K: (16 bn, 16 bm, 2 bz)
    int j = id - 640;
    int bn = j & 15, bm = (j >> 4) & 15, bz = j >> 8;
    rope = true; N = 4096; gain = 1.0f; posbase = bm * 256;
    Ag = hsb + (long)bz * 4096 * 4096 + (long)bm * 256 * 4096;
    Bg = wkb + (long)bn * 256 * 4096;
    Cb = kob + (long)bz * 4096 * 4096 + (long)bm * 256 * 4096 + bn * 256;
  }

  const int w = tid >> 6, lane = tid & 63;
  const int wm = w >> 2, wn = w & 3;
  const int fr = lane & 15, fg = lane >> 4;
  const int ao0 = fr * 64 + ((fg ^ (fr & 7)) * 8);
  const int ao1 = fr * 64 + (((4 + fg) ^ (fr & 7)) * 8);
  const int srow = tid >> 3;
  const int sslot = (tid & 7) ^ (srow & 7);

  // B-fragment row mapping: plain = wn*64+nf*16; rope = head-paired halves
  const unsigned short* brw =
      lds + 32768 + (wn >> 1) * 16384 + (rope ? (wn & 1) * 2048 : (wn & 1) * 4096);
  int boff[4];
#pragma unroll
  for (int nf = 0; nf < 4; ++nf)
    boff[nf] = rope ? ((nf & 1) * 1024 + (nf >> 1) * 4096) : nf * 1024;

  f32x4 acc[8][4] = {};
  bf16x8 a[4][2], b[4][2];

  STG2(Ag, lds + 0, 0, 0);     STG2(Ag, lds + 16384, 1, 0);
  STG2(Bg, lds + 32768, 0, 0); STG2(Bg, lds + 49152, 1, 0);
  STG2(Ag, lds + 8192, 0, 64);  STG2(Ag, lds + 24576, 1, 64);
  STG2(Bg, lds + 40960, 0, 64); STG2(Bg, lds + 57344, 1, 64);
  asm volatile("s_waitcnt vmcnt(8)" ::: "memory");
  asm volatile("s_barrier" ::: "memory");

  for (int ti = 0; ti < 31; ++ti) {        // tiles 0..61
    TILE(0, (2 * ti + 2) * 64, 0);
    TILE(1, (2 * ti + 3) * 64, 0);
  }
  TILE(0, 0, 1);
  TILE(1, 0, 2);

  if (rope) {
    const int head = wn >> 1, q = wn & 1;
#pragma unroll
    for (int mf = 0; mf < 8; ++mf)
#pragma unroll
      for (int nf = 0; nf < 2; ++nf)
#pragma unroll
        for (int rr = 0; rr < 4; ++rr) {
          int row = wm * 128 + mf * 16 + fg * 4 + rr;
          int pos = posbase + row;
          int d = q * 32 + nf * 16 + fr;
          float c = cos_t[pos * 64 + d];
          float s = sin_t[pos * 64 + d];
          float x1 = acc[mf][nf][rr];
          float x2 = acc[mf][nf + 2][rr];
          Cb[(long)row * N + head * 128 + d] = f32_to_bf16_bits((x1 * c - x2 * s) * gain);
          Cb[(long)row * N + head * 128 + 64 + d] =
              f32_to_bf16_bits((x2 * c + x1 * s) * gain);
        }
  } else {
#pragma unroll
    for (int mf = 0; mf < 8; ++mf)
#pragma unroll
      for (int nf = 0; nf < 4; ++nf)
#pragma unroll
        for (int rr = 0; rr < 4; ++rr) {
          int row = wm * 128 + mf * 16 + fg * 4 + rr;
          int col = wn * 64 + nf * 16 + fr;
          Cb[(long)row * N + col] = f32_to_bf16_bits(acc[mf][nf][rr]);
        }
  }
}

// ---- plain 256^2 GEMM (f32 out) for the O projection ----
template <typename OUT_T>
__global__ __launch_bounds__(512, 2) void gemm256(const unsigned short* __restrict__ A,
                                                  const unsigned short* __restrict__ B,
                                                  OUT_T* __restrict__ C,
                                                  long Astride_z, long Cstride_z, int N) {
  __shared__ unsigned short lds[65536];
  const int tid = threadIdx.x;
  const int bn = blockIdx.x, bm = blockIdx.y, bz = blockIdx.z;
  const unsigned short* Ag = A + (long)bz * Astride_z + (long)bm * 256 * 4096;
  const unsigned short* Bg = B + (long)bn * 256 * 4096;

  const int w = tid >> 6, lane = tid & 63;
  const int wm = w >> 2, wn = w & 3;
  const int fr = lane & 15, fg = lane >> 4;
  const int ao0 = fr * 64 + ((fg ^ (fr & 7)) * 8);
  const int ao1 = fr * 64 + (((4 + fg) ^ (fr & 7)) * 8);
  const int srow = tid >> 3;
  const int sslot = (tid & 7) ^ (srow & 7);

  const unsigned short* brw = lds + 32768 + (wn >> 1) * 16384 + (wn & 1) * 4096;
  int boff[4];
#pragma unroll
  for (int nf = 0; nf < 4; ++nf) boff[nf] = nf * 1024;

  f32x4 acc[8][4] = {};
  bf16x8 a[4][2], b[4][2];

  STG2(Ag, lds + 0, 0, 0);     STG2(Ag, lds + 16384, 1, 0);
  STG2(Bg, lds + 32768, 0, 0); STG2(Bg, lds + 49152, 1, 0);
  STG2(Ag, lds + 8192, 0, 64);  STG2(Ag, lds + 24576, 1, 64);
  STG2(Bg, lds + 40960, 0, 64); STG2(Bg, lds + 57344, 1, 64);
  asm volatile("s_waitcnt vmcnt(8)" ::: "memory");
  asm volatile("s_barrier" ::: "memory");

  for (int ti = 0; ti < 31; ++ti) {
    TILE(0, (2 * ti + 2) * 64, 0);
    TILE(1, (2 * ti + 3) * 64, 0);
  }
  TILE(0, 0, 1);
  TILE(1, 0, 2);

  OUT_T* Cb = C + (long)bz * Cstride_z + ((long)bm * 256) * N + bn * 256;
#pragma unroll
  for (int mf = 0; mf < 8; ++mf)
#pragma unroll
    for (int nf = 0; nf < 4; ++nf)
#pragma unroll
      for (int rr = 0; rr < 4; ++rr) {
        int row = wm * 128 + mf * 16 + fg * 4 + rr;
        int col = wn * 64 + nf * 16 + fr;
        storeC(Cb + (long)row * N + col, acc[mf][nf][rr]);
      }
}

// ---- flash attention (R17: XCD swizzle, reversed kv-loop, dbuf, setprio) ----
__global__ __launch_bounds__(256) void attn_fwd(const unsigned short* __restrict__ qb,
                                                const unsigned short* __restrict__ kb,
                                                const unsigned short* __restrict__ vT,
                                                unsigned short* __restrict__ ob) {
  __shared__ unsigned short Ks[2][64 * 128];   // 16KB x2
  __shared__ unsigned short Vl[2][128 * 64];   // 16KB x2
  __shared__ unsigned short Ps[4][16 * 72];    // 9KB

  const int id = blockIdx.x;
  const int xcd = id & 7, j = id >> 3;
  const int hb = xcd + 8 * (j >> 4);
  const int qt = j & 15;
  const int h = hb & 31, b = hb >> 5;

  const int tid = threadIdx.x, w = tid >> 6, lane = tid & 63;
  const int fr = lane & 15, fg = lane >> 4;

  const unsigned short* kbase = kb + (long)b * 4096 * 4096 + h * 128;
  const unsigned short* vbase = vT + (long)h * 128 * 8192 + (long)b * 4096;

  // persistent staging pointers, starting at tile 62 and DECREMENTING
  const unsigned short* kp[4];
  const unsigned short* vp[4];
  unsigned short* kl[4];
  unsigned short* vl[4];
#pragma unroll
  for (int i = 0; i < 4; i++) {
    int c = tid + 256 * i;
    int key = c >> 4, s0 = c & 15;
    kp[i] = kbase + (long)(62 * 64 + key) * 4096 + (s0 ^ (key & 15)) * 8;
    kl[i] = (unsigned short*)&Ks[0][c * 8];
    int f0 = c >> 3, s1 = c & 7;
    vp[i] = vbase + (long)f0 * 8192 + 62 * 64 + (s1 ^ (f0 & 7)) * 8;
    vl[i] = (unsigned short*)&Vl[0][c * 8];
  }
  const int pelem = 64 * 128;

  // Q fragments: row = fr, k = fg*8 + c*32
  bf16x8 qf[4];
  {
    const unsigned short* qptr =
        qb + ((long)b * 1024 + qt * 64 + w * 16 + fr) * 4096 + h * 128 + fg * 8;
#pragma unroll
    for (int c = 0; c < 4; c++) qf[c] = *reinterpret_cast<const bf16x8*>(qptr + c * 32);
  }

  f32x4 outa[8] = {};
  float m_run[4], l_run[4];
#pragma unroll
  for (int r = 0; r < 4; r++) { m_run[r] = -1e30f; l_run[r] = 0.0f; }

  // prologue: stage tile 63 (freshest K rows, L2-warm) into parity 0
#pragma unroll
  for (int i = 0; i < 4; i++) {
    int c = tid + 256 * i;
    int key = c >> 4, s0 = c & 15;
    load_lds16(kbase + (long)(63 * 64 + key) * 4096 + (s0 ^ (key & 15)) * 8,
               &Ks[0][c * 8]);
    int f0 = c >> 3, s1 = c & 7;
    load_lds16(vbase + (long)f0 * 8192 + 63 * 64 + (s1 ^ (f0 & 7)) * 8,
               &Vl[0][c * 8]);
  }
  asm volatile("s_waitcnt vmcnt(0)" ::: "memory");
  asm volatile("s_barrier" ::: "memory");

  for (int it = 0; it < 64; ++it) {   // processes tile 63-it
    const int cur = it & 1;
    if (it < 63) {
      const int po = (cur ^ 1) * pelem;
#pragma unroll
      for (int i = 0; i < 4; i++) {
        load_lds16(kp[i], kl[i] + po);
        kp[i] -= 64 * 4096;
        load_lds16(vp[i], vl[i] + po);
        vp[i] -= 64;
      }
    }

    // S = Q K^T : 4 key-subtiles of 16
    f32x4 sacc[4];
    __builtin_amdgcn_s_setprio(1);
#pragma unroll
    for (int ks = 0; ks < 4; ks++) {
      f32x4 aq = {0.f, 0.f, 0.f, 0.f};
#pragma unroll
      for (int cc = 0; cc < 4; cc++) {
        bf16x8 kf = *reinterpret_cast<const bf16x8*>(
            &Ks[cur][(ks * 16 + fr) * 128 + (((cc * 4 + fg) ^ fr) & 15) * 8]);
        aq = __builtin_amdgcn_mfma_f32_16x16x32_bf16(qf[cc], kf, aq, 0, 0, 0);
      }
      sacc[ks] = aq;
    }
    __builtin_amdgcn_s_setprio(0);

    // per-lane defer-max (cross-lane reduce only when bound triggers)
    float mxl[4];
    int need = 0;
#pragma unroll
    for (int r = 0; r < 4; r++) {
      mxl[r] = fmaxf(fmaxf(sacc[0][r], sacc[1][r]), fmaxf(sacc[2][r], sacc[3][r]));
      need |= (mxl[r] > m_run[r] + 11.5f) ? 1 : 0;
    }
    if (__any(need)) {   // rare: full row max reduce + rescale
#pragma unroll
      for (int r = 0; r < 4; r++) {
        float mx = mxl[r];
        mx = fmaxf(mx, __shfl_xor(mx, 1));
        mx = fmaxf(mx, __shfl_xor(mx, 2));
        mx = fmaxf(mx, __shfl_xor(mx, 4));
        mx = fmaxf(mx, __shfl_xor(mx, 8));
        float mnew = fmaxf(m_run[r], mx);
        float ef = exp2f(m_run[r] - mnew);
        l_run[r] *= ef;
        m_run[r] = mnew;
#pragma unroll
        for (int ds = 0; ds < 8; ds++) outa[ds][r] *= ef;
      }
    }
#pragma unroll
    for (int r = 0; r < 4; r++) {
      float sum = 0.f;
#pragma unroll
      for (int ks = 0; ks < 4; ks++) {
        float pv = exp2f(sacc[ks][r] - m_run[r]);   // <= 2^11.5
        Ps[w][(fg * 4 + r) * 72 + ks * 16 + fr] = f32_to_bf16_fast(pv);
        sum += pv;
      }
      l_run[r] += sum;
    }

    // O += P V
    __builtin_amdgcn_s_setprio(1);
#pragma unroll
    for (int c2 = 0; c2 < 2; c2++) {
      bf16x8 pf = *reinterpret_cast<const bf16x8*>(&Ps[w][fr * 72 + c2 * 32 + fg * 8]);
#pragma unroll
      for (int ds = 0; ds < 8; ds++) {
        int feat = ds * 16 + fr;
        int pch = ((c2 * 4 + fg) ^ (feat & 7)) & 7;
        bf16x8 vf = *reinterpret_cast<const bf16x8*>(&Vl[cur][feat * 64 + pch * 8]);
        outa[ds] = __builtin_amdgcn_mfma_f32_16x16x32_bf16(pf, vf, outa[ds], 0, 0, 0);
      }
    }
    __builtin_amdgcn_s_setprio(0);

    if (it < 63) {
      asm volatile("s_waitcnt vmcnt(0) lgkmcnt(0)" ::: "memory");
      asm volatile("s_barrier" ::: "memory");
    }
  }

  // final cross-lane l reduce (16 fr lanes), normalize, store
#pragma unroll
  for (int r = 0; r < 4; r++) {
    float l = l_run[r];
    l += __shfl_xor(l, 1);
    l += __shfl_xor(l, 2);
    l += __shfl_xor(l, 4);
    l += __shfl_xor(l, 8);
    float inv = 1.0f / l;
    unsigned short* op =
        ob + ((long)b * 1024 + qt * 64 + w * 16 + fg * 4 + r) * 4096 + h * 128;
#pragma unroll
    for (int ds = 0; ds < 8; ds++) op[ds * 16 + fr] = f32_to_bf16_bits(outa[ds][r] * inv);
  }
}

// ---------------------------------------------------------------------------
extern "C" void kernel_launch(void* const* d_in, const int* in_sizes, int n_in,
                              void* d_out, int out_size, void* d_ws, size_t ws_size,
                              hipStream_t stream) {
  const float* hs = (const float*)d_in[0];
  const float* wq = (const float*)d_in[1];
  const float* wk = (const float*)d_in[2];
  const float* wv = (const float*)d_in[3];
  const float* wo = (const float*)d_in[4];
  float* out = (float*)d_out;

  const long hsN = 2L * 4096 * 4096;
  const long wN  = 4096L * 4096;

  unsigned short* hs_b = (unsigned short*)d_ws;
  unsigned short* wq_b = hs_b + hsN;
  unsigned short* wk_b = wq_b + wN;
  unsigned short* wv_b = wk_b + wN;
  unsigned short* wo_b = wv_b + wN;
  unsigned short* q_b  = wo_b + wN;             // 2048 x 4096
  unsigned short* k_b  = q_b + 2048L * 4096;    // 8192 x 4096 ([tok][feat])
  unsigned short* vT_b = k_b + 8192L * 4096;    // 4096 x 8192 ([feat][tok])
  unsigned short* at_b = vT_b + 8192L * 4096;   // 2048 x 4096
  float* cos_t = (float*)(at_b + 2048L * 4096);
  float* sin_t = cos_t + 4096 * 64;

  cast_f32_bf16_batched<<<dim3(8192), dim3(256), 0, stream>>>(
      hs, wq, wk, wv, wo, hs_b);

  rope_tables<<<dim3(1024), dim3(256), 0, stream>>>(cos_t, sin_t);

  // fused vT + Q + K (K last => L2-warm tail for the reversed attn loop)
  const float qgain = 0.08838834764831845f * 1.4426950408889634f;
  gemm_qkv<<<dim3(1152), dim3(512), 0, stream>>>(
      hs_b, wv_b, wq_b, wk_b, vT_b, q_b, k_b, cos_t, sin_t, qgain);

  // attention — flat grid with XCD-aware decode; kv-loop runs high->low
  attn_fwd<<<dim3(1024), dim3(256), 0, stream>>>(q_b, k_b, vT_b, at_b);

  // O projection — plain 256^2, f32 out
  gemm256<float><<<dim3(16, 8, 1), dim3(512), 0, stream>>>(
      at_b, wo_b, out, 0L, 0L, 4096);
}

// Round 19
// 966.460 us; speedup vs baseline: 1.0412x; 1.0172x over previous
//
#include <hip/hip_runtime.h>
#include <hip/hip_bf16.h>

// ---------------------------------------------------------------------------
// RingLlamaAttention on MI355X (gfx950)
// batched cast f32->bf16 (+rope tables fused) | FUSED vT+Q+K gemm (1152
// blocks; 256^2 pipelined, RoPE fused for Q/K, K region last => L2-warm) |
// flash attention (QBLK=64, reversed kv-loop, K+V dbuf via gload_lds,
// XCD-aware swizzle, per-lane defer-max, exp2 softmax, deferred l-reduce,
// setprio) | O gemm SPLIT-K (256 blocks, f32 partials) + add -> f32 out
// Shapes: B=2, S=4096, s_local=1024, H=4096, nh=32, hd=128, K=4096
// ---------------------------------------------------------------------------

using bf16x8 = __attribute__((ext_vector_type(8))) short;
using f32x4  = __attribute__((ext_vector_type(4))) float;

__device__ inline unsigned short f32_to_bf16_bits(float f) {
  unsigned int u = __float_as_uint(f);
  u += 0x7FFFu + ((u >> 16) & 1u);   // round-to-nearest-even
  return (unsigned short)(u >> 16);
}
__device__ inline float bf16_bits_to_f32(unsigned short h) {
  return __uint_as_float(((unsigned int)h) << 16);
}
__device__ inline unsigned short f32_to_bf16_fast(float f) {
  __hip_bfloat16 hb = __float2bfloat16(f);
  unsigned short us;
  __builtin_memcpy(&us, &hb, 2);
  return us;
}

// async global->LDS, 16B per lane (dest must be wave-uniform base + lane*16)
__device__ __forceinline__ void load_lds16(const unsigned short* g, unsigned short* l) {
  __builtin_amdgcn_global_load_lds(
      (const __attribute__((address_space(1))) void*)g,
      (__attribute__((address_space(3))) void*)l, 16, 0, 0);
}

// ---- batched f32 -> bf16 cast + rope table generation (fused tail) ----
__global__ void cast_f32_bf16_batched(const float* __restrict__ hs,
                                      const float* __restrict__ w0,
                                      const float* __restrict__ w1,
                                      const float* __restrict__ w2,
                                      const float* __restrict__ w3,
                                      unsigned short* __restrict__ out,
                                      float* __restrict__ cos_t,
                                      float* __restrict__ sin_t) {
  const long hs4 = 2L * 4096 * 4096 / 4;
  const long w4  = 4096L * 4096 / 4;
  long i = (long)blockIdx.x * blockDim.x + threadIdx.x;
  const long gsz = (long)gridDim.x * blockDim.x;
  const long total = hs4 + 4 * w4;
  for (long ii = i; ii < total; ii += gsz) {
    const float* src;
    long j = ii;
    if (j < hs4) { src = hs; }
    else {
      j -= hs4;
      long wi = j / w4;
      j -= wi * w4;
      src = (wi == 0) ? w0 : (wi == 1) ? w1 : (wi == 2) ? w2 : w3;
    }
    float4 v = reinterpret_cast<const float4*>(src)[j];
    ushort4 o;
    o.x = f32_to_bf16_bits(v.x);
    o.y = f32_to_bf16_bits(v.y);
    o.z = f32_to_bf16_bits(v.z);
    o.w = f32_to_bf16_bits(v.w);
    reinterpret_cast<ushort4*>(out)[ii] = o;
  }
  // rope tables: first 262144 global threads
  if (i < 4096 * 64) {
    int p = (int)(i >> 6), fi = (int)(i & 63);
    float inv = __expf(-(float)fi * (9.210340371976184f / 64.0f));
    float f = (float)p * inv;
    cos_t[i] = cosf(f);
    sin_t[i] = sinf(f);
  }
}

__device__ inline void storeC(float* p, float v) { *p = v; }
__device__ inline void storeC(unsigned short* p, float v) { *p = f32_to_bf16_bits(v); }

// ---- 256^2 depth-2 pipelined GEMM core macros (verified R5 ledger) ----
#define STG2(Gb, Lb, h, kc)                                                    \
  load_lds16((Gb) + (long)((h) * 128 + srow) * 4096 + sslot * 8 + (kc),        \
             (Lb) + tid * 8);                                                  \
  load_lds16((Gb) + (long)((h) * 128 + 64 + srow) * 4096 + sslot * 8 + (kc),   \
             (Lb) + 4096 + tid * 8);

#define MFMAQ(MH, NH)                                                          \
  _Pragma("unroll") for (int mi = 0; mi < 4; ++mi)                             \
    _Pragma("unroll") for (int ni = 0; ni < 2; ++ni)                           \
      _Pragma("unroll") for (int kk = 0; kk < 2; ++kk)                         \
        acc[(MH) * 4 + mi][(NH) * 2 + ni] =                                    \
            __builtin_amdgcn_mfma_f32_16x16x32_bf16(                           \
                a[mi][kk], b[(NH) * 2 + ni][kk],                               \
                acc[(MH) * 4 + mi][(NH) * 2 + ni], 0, 0, 0);

#define TILE(P, KC, MODE)                                                      \
  {                                                                            \
    const unsigned short* Ar = lds + wm * 16384 + (P) * 8192;                  \
    const unsigned short* Br = brw + (P) * 8192;                               \
    _Pragma("unroll") for (int mf = 0; mf < 4; ++mf) {                         \
      a[mf][0] = *reinterpret_cast<const bf16x8*>(Ar + mf * 1024 + ao0);       \
      a[mf][1] = *reinterpret_cast<const bf16x8*>(Ar + mf * 1024 + ao1);       \
    }                                                                          \
    _Pragma("unroll") for (int nf = 0; nf < 2; ++nf) {                         \
      b[nf][0] = *reinterpret_cast<const bf16x8*>(Br + boff[nf] + ao0);        \
      b[nf][1] = *reinterpret_cast<const bf16x8*>(Br + boff[nf] + ao1);        \
    }                                                                          \
    __builtin_amdgcn_s_setprio(1);                                             \
    MFMAQ(0, 0);                                                               \
    __builtin_amdgcn_s_setprio(0);                                             \
    _Pragma("unroll") for (int nf = 2; nf < 4; ++nf) {                         \
      b[nf][0] = *reinterpret_cast<const bf16x8*>(Br + boff[nf] + ao0);        \
      b[nf][1] = *reinterpret_cast<const bf16x8*>(Br + boff[nf] + ao1);        \
    }                                                                          \
    __builtin_amdgcn_s_setprio(1);                                             \
    MFMAQ(0, 1);                                                               \
    __builtin_amdgcn_s_setprio(0);                                             \
    asm volatile("s_waitcnt lgkmcnt(0)" ::: "memory");                         \
    asm volatile("s_barrier" ::: "memory"); /* B[.][P] fully read */           \
    if ((MODE) == 0) {                                                         \
      STG2(Bg, lds + 32768 + (P) * 8192, 0, KC);                               \
      STG2(Bg, lds + 49152 + (P) * 8192, 1, KC);                               \
    }                                                                          \
    _Pragma("unroll") for (int mf = 0; mf < 4; ++mf) {                         \
      a[mf][0] = *reinterpret_cast<const bf16x8*>(Ar + (4 + mf) * 1024 + ao0); \
      a[mf][1] = *reinterpret_cast<const bf16x8*>(Ar + (4 + mf) * 1024 + ao1); \
    }                                                                          \
    __builtin_amdgcn_s_setprio(1);                                             \
    MFMAQ(1, 0);                                                               \
    __builtin_amdgcn_s_setprio(0);                                             \
    asm volatile("s_waitcnt lgkmcnt(0)" ::: "memory");                         \
    asm volatile("s_barrier" ::: "memory"); /* A[.][P] fully read */           \
    if ((MODE) == 0) {                                                         \
      STG2(Ag, lds + (P) * 8192, 0, KC);                                       \
      STG2(Ag, lds + 16384 + (P) * 8192, 1, KC);                               \
    }                                                                          \
    __builtin_amdgcn_s_setprio(1);                                             \
    MFMAQ(1, 1);                                                               \
    __builtin_amdgcn_s_setprio(0);                                             \
    if ((MODE) == 0) asm volatile("s_waitcnt vmcnt(8)" ::: "memory");          \
    if ((MODE) == 1) asm volatile("s_waitcnt vmcnt(0)" ::: "memory");          \
    asm volatile("s_barrier" ::: "memory"); /* next tile's data landed */      \
  }

// ---- fused vT + Q + K launch: 1152 blocks, block-uniform region decode ----
__global__ __launch_bounds__(512, 2) void gemm_qkv(
    const unsigned short* __restrict__ hsb, const unsigned short* __restrict__ wvb,
    const unsigned short* __restrict__ wqb, const unsigned short* __restrict__ wkb,
    unsigned short* __restrict__ vTb, unsigned short* __restrict__ qob,
    unsigned short* __restrict__ kob, const float* __restrict__ cos_t,
    const float* __restrict__ sin_t, float qgain) {
  __shared__ unsigned short lds[65536];   // 128 KiB
  const int tid = threadIdx.x;
  const int id = blockIdx.x;

  const unsigned short *Ag, *Bg;
  unsigned short* Cb;
  int N, posbase;
  float gain;
  bool rope;
  if (id < 512) {                       // vT: A=wv (16 bm), B=hs (32 bn)
    int bn = id & 31, bm = id >> 5;
    rope = false; N = 8192; gain = 1.0f; posbase = 0;
    Ag = wvb + (long)bm * 256 * 4096;
    Bg = hsb + (long)bn * 256 * 4096;
    Cb = vTb + (long)bm * 256 * 8192 + bn * 256;
  } else if (id < 640) {                // Q: (16 bn, 4 bm, 2 bz)
    int j = id - 512;
    int bn = j & 15, bm = (j >> 4) & 3, bz = j >> 6;
    rope = true; N = 4096; gain = qgain; posbase = bm * 256;
    Ag = hsb + (long)bz * 4096 * 4096 + (long)bm * 256 * 4096;
    Bg = wqb + (long)bn * 256 * 4096;
    Cb = qob + (long)bz * 1024 * 4096 + (long)bm * 256 * 4096 + bn * 256;
  } else {                              // K: (16 bn, 16 bm, 2 bz)
    int j = id - 640;
    int bn = j & 15, bm = (j >> 4) & 15, bz = j >> 8;
    rope = true; N = 4096; gain = 1.0f; posbase = bm * 256;
    Ag = hsb + (long)bz * 4096 * 4096 + (long)bm * 256 * 4096;
    Bg = wkb + (long)bn * 256 * 4096;
    Cb = kob + (long)bz * 4096 * 4096 + (long)bm * 256 * 4096 + bn * 256;
  }

  const int w = tid >> 6, lane = tid & 63;
  const int wm = w >> 2, wn = w & 3;
  const int fr = lane & 15, fg = lane >> 4;
  const int ao0 = fr * 64 + ((fg ^ (fr & 7)) * 8);
  const int ao1 = fr * 64 + (((4 + fg) ^ (fr & 7)) * 8);
  const int srow = tid >> 3;
  const int sslot = (tid & 7) ^ (srow & 7);

  const unsigned short* brw =
      lds + 32768 + (wn >> 1) * 16384 + (rope ? (wn & 1) * 2048 : (wn & 1) * 4096);
  int boff[4];
#pragma unroll
  for (int nf = 0; nf < 4; ++nf)
    boff[nf] = rope ? ((nf & 1) * 1024 + (nf >> 1) * 4096) : nf * 1024;

  f32x4 acc[8][4] = {};
  bf16x8 a[4][2], b[4][2];

  STG2(Ag, lds + 0, 0, 0);     STG2(Ag, lds + 16384, 1, 0);
  STG2(Bg, lds + 32768, 0, 0); STG2(Bg, lds + 49152, 1, 0);
  STG2(Ag, lds + 8192, 0, 64);  STG2(Ag, lds + 24576, 1, 64);
  STG2(Bg, lds + 40960, 0, 64); STG2(Bg, lds + 57344, 1, 64);
  asm volatile("s_waitcnt vmcnt(8)" ::: "memory");
  asm volatile("s_barrier" ::: "memory");

  for (int ti = 0; ti < 31; ++ti) {        // tiles 0..61
    TILE(0, (2 * ti + 2) * 64, 0);
    TILE(1, (2 * ti + 3) * 64, 0);
  }
  TILE(0, 0, 1);
  TILE(1, 0, 2);

  if (rope) {
    const int head = wn >> 1, q = wn & 1;
#pragma unroll
    for (int mf = 0; mf < 8; ++mf)
#pragma unroll
      for (int nf = 0; nf < 2; ++nf)
#pragma unroll
        for (int rr = 0; rr < 4; ++rr) {
          int row = wm * 128 + mf * 16 + fg * 4 + rr;
          int pos = posbase + row;
          int d = q * 32 + nf * 16 + fr;
          float c = cos_t[pos * 64 + d];
          float s = sin_t[pos * 64 + d];
          float x1 = acc[mf][nf][rr];
          float x2 = acc[mf][nf + 2][rr];
          Cb[(long)row * N + head * 128 + d] = f32_to_bf16_bits((x1 * c - x2 * s) * gain);
          Cb[(long)row * N + head * 128 + 64 + d] =
              f32_to_bf16_bits((x2 * c + x1 * s) * gain);
        }
  } else {
#pragma unroll
    for (int mf = 0; mf < 8; ++mf)
#pragma unroll
      for (int nf = 0; nf < 4; ++nf)
#pragma unroll
        for (int rr = 0; rr < 4; ++rr) {
          int row = wm * 128 + mf * 16 + fg * 4 + rr;
          int col = wn * 64 + nf * 16 + fr;
          Cb[(long)row * N + col] = f32_to_bf16_bits(acc[mf][nf][rr]);
        }
  }
}

// ---- O projection, split-K: 256 blocks, each half of K (32 tiles) -> f32 ----
__global__ __launch_bounds__(512, 2) void gemm_o_split(
    const unsigned short* __restrict__ A, const unsigned short* __restrict__ B,
    float* __restrict__ P0, float* __restrict__ P1) {
  __shared__ unsigned short lds[65536];
  const int tid = threadIdx.x;
  const int id = blockIdx.x;
  const int half = id >> 7, j = id & 127;
  const int bn = j & 15, bm = j >> 4;
  const int koff = half * 2048;

  const unsigned short* Ag = A + (long)bm * 256 * 4096 + koff;
  const unsigned short* Bg = B + (long)bn * 256 * 4096 + koff;
  float* Cb = (half ? P1 : P0) + (long)bm * 256 * 4096 + bn * 256;

  const int w = tid >> 6, lane = tid & 63;
  const int wm = w >> 2, wn = w & 3;
  const int fr = lane & 15, fg = lane >> 4;
  const int ao0 = fr * 64 + ((fg ^ (fr & 7)) * 8);
  const int ao1 = fr * 64 + (((4 + fg) ^ (fr & 7)) * 8);
  const int srow = tid >> 3;
  const int sslot = (tid & 7) ^ (srow & 7);

  const unsigned short* brw = lds + 32768 + (wn >> 1) * 16384 + (wn & 1) * 4096;
  int boff[4];
#pragma unroll
  for (int nf = 0; nf < 4; ++nf) boff[nf] = nf * 1024;

  f32x4 acc[8][4] = {};
  bf16x8 a[4][2], b[4][2];

  STG2(Ag, lds + 0, 0, 0);     STG2(Ag, lds + 16384, 1, 0);
  STG2(Bg, lds + 32768, 0, 0); STG2(Bg, lds + 49152, 1, 0);
  STG2(Ag, lds + 8192, 0, 64);  STG2(Ag, lds + 24576, 1, 64);
  STG2(Bg, lds + 40960, 0, 64); STG2(Bg, lds + 57344, 1, 64);
  asm volatile("s_waitcnt vmcnt(8)" ::: "memory");
  asm volatile("s_barrier" ::: "memory");

  for (int ti = 0; ti < 15; ++ti) {        // tiles 0..29 of this half
    TILE(0, (2 * ti + 2) * 64, 0);
    TILE(1, (2 * ti + 3) * 64, 0);
  }
  TILE(0, 0, 1);                           // tile 30
  TILE(1, 0, 2);                           // tile 31

#pragma unroll
  for (int mf = 0; mf < 8; ++mf)
#pragma unroll
    for (int nf = 0; nf < 4; ++nf)
#pragma unroll
      for (int rr = 0; rr < 4; ++rr) {
        int row = wm * 128 + mf * 16 + fg * 4 + rr;
        int col = wn * 64 + nf * 16 + fr;
        Cb[(long)row * 4096 + col] = acc[mf][nf][rr];
      }
}

// ---- final add: out = P0 + P1 (float4 vectorized) ----
__global__ void add_out(const float4* __restrict__ p0, const float4* __restrict__ p1,
                        float4* __restrict__ out, long n4) {
  long i = (long)blockIdx.x * blockDim.x + threadIdx.x;
  long stride = (long)gridDim.x * blockDim.x;
  for (; i < n4; i += stride) {
    float4 x = p0[i], y = p1[i];
    float4 r;
    r.x = x.x + y.x; r.y = x.y + y.y; r.z = x.z + y.z; r.w = x.w + y.w;
    out[i] = r;
  }
}

// ---- flash attention (R17: XCD swizzle, reversed kv-loop, dbuf, setprio) ----
__global__ __launch_bounds__(256) void attn_fwd(const unsigned short* __restrict__ qb,
                                                const unsigned short* __restrict__ kb,
                                                const unsigned short* __restrict__ vT,
                                                unsigned short* __restrict__ ob) {
  __shared__ unsigned short Ks[2][64 * 128];   // 16KB x2
  __shared__ unsigned short Vl[2][128 * 64];   // 16KB x2
  __shared__ unsigned short Ps[4][16 * 72];    // 9KB

  const int id = blockIdx.x;
  const int xcd = id & 7, j = id >> 3;
  const int hb = xcd + 8 * (j >> 4);
  const int qt = j & 15;
  const int h = hb & 31, b = hb >> 5;

  const int tid = threadIdx.x, w = tid >> 6, lane = tid & 63;
  const int fr = lane & 15, fg = lane >> 4;

  const unsigned short* kbase = kb + (long)b * 4096 * 4096 + h * 128;
  const unsigned short* vbase = vT + (long)h * 128 * 8192 + (long)b * 4096;

  // persistent staging pointers, starting at tile 62 and DECREMENTING
  const unsigned short* kp[4];
  const unsigned short* vp[4];
  unsigned short* kl[4];
  unsigned short* vl[4];
#pragma unroll
  for (int i = 0; i < 4; i++) {
    int c = tid + 256 * i;
    int key = c >> 4, s0 = c & 15;
    kp[i] = kbase + (long)(62 * 64 + key) * 4096 + (s0 ^ (key & 15)) * 8;
    kl[i] = (unsigned short*)&Ks[0][c * 8];
    int f0 = c >> 3, s1 = c & 7;
    vp[i] = vbase + (long)f0 * 8192 + 62 * 64 + (s1 ^ (f0 & 7)) * 8;
    vl[i] = (unsigned short*)&Vl[0][c * 8];
  }
  const int pelem = 64 * 128;

  // Q fragments: row = fr, k = fg*8 + c*32
  bf16x8 qf[4];
  {
    const unsigned short* qptr =
        qb + ((long)b * 1024 + qt * 64 + w * 16 + fr) * 4096 + h * 128 + fg * 8;
#pragma unroll
    for (int c = 0; c < 4; c++) qf[c] = *reinterpret_cast<const bf16x8*>(qptr + c * 32);
  }

  f32x4 outa[8] = {};
  float m_run[4], l_run[4];
#pragma unroll
  for (int r = 0; r < 4; r++) { m_run[r] = -1e30f; l_run[r] = 0.0f; }

  // prologue: stage tile 63 (freshest K rows, L2-warm) into parity 0
#pragma unroll
  for (int i = 0; i < 4; i++) {
    int c = tid + 256 * i;
    int key = c >> 4, s0 = c & 15;
    load_lds16(kbase + (long)(63 * 64 + key) * 4096 + (s0 ^ (key & 15)) * 8,
               &Ks[0][c * 8]);
    int f0 = c >> 3, s1 = c & 7;
    load_lds16(vbase + (long)f0 * 8192 + 63 * 64 + (s1 ^ (f0 & 7)) * 8,
               &Vl[0][c * 8]);
  }
  asm volatile("s_waitcnt vmcnt(0)" ::: "memory");
  asm volatile("s_barrier" ::: "memory");

  for (int it = 0; it < 64; ++it) {   // processes tile 63-it
    const int cur = it & 1;
    if (it < 63) {
      const int po = (cur ^ 1) * pelem;
#pragma unroll
      for (int i = 0; i < 4; i++) {
        load_lds16(kp[i], kl[i] + po);
        kp[i] -= 64 * 4096;
        load_lds16(vp[i], vl[i] + po);
        vp[i] -= 64;
      }
    }

    // S = Q K^T : 4 key-subtiles of 16
    f32x4 sacc[4];
    __builtin_amdgcn_s_setprio(1);
#pragma unroll
    for (int ks = 0; ks < 4; ks++) {
      f32x4 aq = {0.f, 0.f, 0.f, 0.f};
#pragma unroll
      for (int cc = 0; cc < 4; cc++) {
        bf16x8 kf = *reinterpret_cast<const bf16x8*>(
            &Ks[cur][(ks * 16 + fr) * 128 + (((cc * 4 + fg) ^ fr) & 15) * 8]);
        aq = __builtin_amdgcn_mfma_f32_16x16x32_bf16(qf[cc], kf, aq, 0, 0, 0);
      }
      sacc[ks] = aq;
    }
    __builtin_amdgcn_s_setprio(0);

    // per-lane defer-max (cross-lane reduce only when bound triggers)
    float mxl[4];
    int need = 0;
#pragma unroll
    for (int r = 0; r < 4; r++) {
      mxl[r] = fmaxf(fmaxf(sacc[0][r], sacc[1][r]), fmaxf(sacc[2][r], sacc[3][r]));
      need |= (mxl[r] > m_run[r] + 11.5f) ? 1 : 0;
    }
    if (__any(need)) {   // rare: full row max reduce + rescale
#pragma unroll
      for (int r = 0; r < 4; r++) {
        float mx = mxl[r];
        mx = fmaxf(mx, __shfl_xor(mx, 1));
        mx = fmaxf(mx, __shfl_xor(mx, 2));
        mx = fmaxf(mx, __shfl_xor(mx, 4));
        mx = fmaxf(mx, __shfl_xor(mx, 8));
        float mnew = fmaxf(m_run[r], mx);
        float ef = exp2f(m_run[r] - mnew);
        l_run[r] *= ef;
        m_run[r] = mnew;
#pragma unroll
        for (int ds = 0; ds < 8; ds++) outa[ds][r] *= ef;
      }
    }
#pragma unroll
    for (int r = 0; r < 4; r++) {
      float sum = 0.f;
#pragma unroll
      for (int ks = 0; ks < 4; ks++) {
        float pv = exp2f(sacc[ks][r] - m_run[r]);   // <= 2^11.5
        Ps[w][(fg * 4 + r) * 72 + ks * 16 + fr] = f32_to_bf16_fast(pv);
        sum += pv;
      }
      l_run[r] += sum;
    }

    // O += P V
    __builtin_amdgcn_s_setprio(1);
#pragma unroll
    for (int c2 = 0; c2 < 2; c2++) {
      bf16x8 pf = *reinterpret_cast<const bf16x8*>(&Ps[w][fr * 72 + c2 * 32 + fg * 8]);
#pragma unroll
      for (int ds = 0; ds < 8; ds++) {
        int feat = ds * 16 + fr;
        int pch = ((c2 * 4 + fg) ^ (feat & 7)) & 7;
        bf16x8 vf = *reinterpret_cast<const bf16x8*>(&Vl[cur][feat * 64 + pch * 8]);
        outa[ds] = __builtin_amdgcn_mfma_f32_16x16x32_bf16(pf, vf, outa[ds], 0, 0, 0);
      }
    }
    __builtin_amdgcn_s_setprio(0);

    if (it < 63) {
      asm volatile("s_waitcnt vmcnt(0) lgkmcnt(0)" ::: "memory");
      asm volatile("s_barrier" ::: "memory");
    }
  }

  // final cross-lane l reduce (16 fr lanes), normalize, store
#pragma unroll
  for (int r = 0; r < 4; r++) {
    float l = l_run[r];
    l += __shfl_xor(l, 1);
    l += __shfl_xor(l, 2);
    l += __shfl_xor(l, 4);
    l += __shfl_xor(l, 8);
    float inv = 1.0f / l;
    unsigned short* op =
        ob + ((long)b * 1024 + qt * 64 + w * 16 + fg * 4 + r) * 4096 + h * 128;
#pragma unroll
    for (int ds = 0; ds < 8; ds++) op[ds * 16 + fr] = f32_to_bf16_bits(outa[ds][r] * inv);
  }
}

// ---------------------------------------------------------------------------
extern "C" void kernel_launch(void* const* d_in, const int* in_sizes, int n_in,
                              void* d_out, int out_size, void* d_ws, size_t ws_size,
                              hipStream_t stream) {
  const float* hs = (const float*)d_in[0];
  const float* wq = (const float*)d_in[1];
  const float* wk = (const float*)d_in[2];
  const float* wv = (const float*)d_in[3];
  const float* wo = (const float*)d_in[4];
  float* out = (float*)d_out;

  const long hsN = 2L * 4096 * 4096;
  const long wN  = 4096L * 4096;

  unsigned short* hs_b = (unsigned short*)d_ws;
  unsigned short* wq_b = hs_b + hsN;
  unsigned short* wk_b = wq_b + wN;
  unsigned short* wv_b = wk_b + wN;
  unsigned short* wo_b = wv_b + wN;
  unsigned short* q_b  = wo_b + wN;             // 2048 x 4096
  unsigned short* k_b  = q_b + 2048L * 4096;    // 8192 x 4096 ([tok][feat])
  unsigned short* vT_b = k_b + 8192L * 4096;    // 4096 x 8192 ([feat][tok])
  unsigned short* at_b = vT_b + 8192L * 4096;   // 2048 x 4096
  float* cos_t = (float*)(at_b + 2048L * 4096);
  float* sin_t = cos_t + 4096 * 64;
  // split-K partials alias hs_b (dead after gemm_qkv): 2 x 8.4M floats
  float* P0 = (float*)hs_b;
  float* P1 = P0 + 2048L * 4096;

  cast_f32_bf16_batched<<<dim3(8192), dim3(256), 0, stream>>>(
      hs, wq, wk, wv, wo, hs_b, cos_t, sin_t);

  // fused vT + Q + K (K last => L2-warm tail for the reversed attn loop)
  const float qgain = 0.08838834764831845f * 1.4426950408889634f;
  gemm_qkv<<<dim3(1152), dim3(512), 0, stream>>>(
      hs_b, wv_b, wq_b, wk_b, vT_b, q_b, k_b, cos_t, sin_t, qgain);

  // attention — flat grid with XCD-aware decode; kv-loop runs high->low
  attn_fwd<<<dim3(1024), dim3(256), 0, stream>>>(q_b, k_b, vT_b, at_b);

  // O projection — split-K over 256 blocks (full GPU), then add
  gemm_o_split<<<dim3(256), dim3(512), 0, stream>>>(at_b, wo_b, P0, P1);
  add_out<<<dim3(2048), dim3(256), 0, stream>>>(
      (const float4*)P0, (const float4*)P1, (float4*)out, 2048L * 4096 / 4);
}